// Round 6
// baseline (214.366 us; speedup 1.0000x reference)
//
#include <hip/hip_runtime.h>
#include <stdint.h>

// ---------------------------------------------------------------------------
// Fused RBF histogram:  hist[o,i] = sum_n exp(-||x_n - c_o||^2 / 2) * x[n,i]
// N=524288, IN=64, OUT=128.  fp32 in/out.
//
// R6: 2-WAVE BLOCKS (barrier radius halved), 32-row strips.
//  - block = 128 thr; wave w owns o-half w (4 o-tiles): c-frags 64 regs,
//    hacc 64 regs. Staging shared (each x element converted exactly once).
//  - barriers sync only 2 waves; 4 independent blocks/CU interleave phases.
//  - stage-B K=32 (one strip): sPw A-frag = single b128 read; sPw [2][64][40].
//  - c pre-scaled by log2e (x kept RAW): staging drops 16 v_mul/thread and
//    the hi(x) bf16 values serve both sXhi and sXT.
//  - LDS 24.7 KB; launch_bounds(128,2) -> 4 blocks/CU.
// ---------------------------------------------------------------------------

typedef __bf16 bf16x8 __attribute__((ext_vector_type(8)));
typedef unsigned short ushortx8 __attribute__((ext_vector_type(8)));
typedef float floatx4 __attribute__((ext_vector_type(4)));

#define GRIDN 1024       // 4 blocks/CU x 256 CUs
#define NSTRIPS 16384    // 524288 / 32
#define LOG2E 1.4426950408889634f

#if __has_builtin(__builtin_amdgcn_exp2f)
#define EXP2F(x) __builtin_amdgcn_exp2f(x)
#else
#define EXP2F(x) exp2f(x)
#endif

// round-to-nearest-even fp32 -> bf16 (bit trick; no NaN inputs here)
static __device__ __forceinline__ unsigned int bfbits(float f) {
  unsigned int u = __float_as_uint(f);
  return u + 0x7fffu + ((u >> 16) & 1u);   // rounded value in high 16 bits
}
// pack two fp32 -> bf16x2 (RNE), a in low half
static __device__ __forceinline__ unsigned int pkbf(float a, float b) {
  return (bfbits(a) >> 16) | (bfbits(b) & 0xffff0000u);
}

static __device__ __forceinline__ floatx4 mfma_bf16(ushortx8 a, ushortx8 b, floatx4 c) {
  return __builtin_amdgcn_mfma_f32_16x16x32_bf16(
      __builtin_bit_cast(bf16x8, a), __builtin_bit_cast(bf16x8, b), c, 0, 0, 0);
}

// sXhi/sXlo stride 72 shorts = 144 B (16B-aligned rows); sXT/sPw stride 40
// shorts = 80 B (16B-aligned). Bank steps 4 / 20 words -> <=2..4-way.
#define LSTR 72
#define PSTR 40

__global__ __launch_bounds__(128, 2) void rbf_hist_kernel(
    const float* __restrict__ x, const float* __restrict__ c,
    float* __restrict__ out, float* __restrict__ ws, int use_ws) {
  __shared__ unsigned short sXhi[32][LSTR];    // bf16 hi(x)      [n][i]
  __shared__ unsigned short sXlo[32][LSTR];    // bf16 lo(x)      [n][i]
  __shared__ unsigned short sXT [64][PSTR];    // bf16 hi(x)^T    [i][n 0..31]
  __shared__ unsigned short sPw [2][64][PSTR]; // per-wave rbf    [o'][n 0..31]
  __shared__ float          sX2 [32];          // -0.5*log2e*||x_n||^2

  const int t    = threadIdx.x;    // 0..127
  const int lane = t & 63;
  const int w    = t >> 6;         // wave 0/1; owns o-tiles {4w..4w+3}
  const int l15  = lane & 15;
  const int quad = lane >> 4;

  // ---- one-time: c*log2e fragments (hi/lo) for this wave's 4 o-tiles ----
  // B-frag stage A: B[k=i][col=o]: lane reads c[ot*16+l15][s*32+quad*8 ..+7]
  uint4 chi[4][2], clo[4][2];
  float m2c[4];                    // -0.5*log2e*||c_o||^2
#pragma unroll
  for (int oo = 0; oo < 4; ++oo) {
    const int ot = 4 * w + oo;
    float sq = 0.f;
#pragma unroll
    for (int s = 0; s < 2; ++s) {
      const float* p = c + (ot * 16 + l15) * 64 + s * 32 + quad * 8;
      float4 va = *(const float4*)(p);
      float4 vb = *(const float4*)(p + 4);
      float f[8] = {va.x, va.y, va.z, va.w, vb.x, vb.y, vb.z, vb.w};
      unsigned int h[4], l[4];
#pragma unroll
      for (int jp = 0; jp < 4; ++jp) {
        float a = f[2 * jp], b = f[2 * jp + 1];
        sq = fmaf(a, a, sq);
        sq = fmaf(b, b, sq);
        a *= LOG2E; b *= LOG2E;               // scale on c side only
        unsigned int hp = pkbf(a, b);
        float la = a - __uint_as_float(hp << 16);
        float lb = b - __uint_as_float(hp & 0xffff0000u);
        h[jp] = hp;
        l[jp] = pkbf(la, lb);
      }
      chi[oo][s] = uint4{h[0], h[1], h[2], h[3]};
      clo[oo][s] = uint4{l[0], l[1], l[2], l[3]};
    }
    sq += __shfl_xor(sq, 16);
    sq += __shfl_xor(sq, 32);
    m2c[oo] = -0.5f * LOG2E * sq;
  }

  // persistent histogram accumulators: 4 o-tiles x 4 i-tiles
  floatx4 hacc[4][4];
#pragma unroll
  for (int a = 0; a < 4; ++a)
#pragma unroll
    for (int b = 0; b < 4; ++b) {
      floatx4 z = {0.f, 0.f, 0.f, 0.f};
      hacc[a][b] = z;
    }

  // staging map: thread t -> row r=t>>2 (0..31), cols q*4+g*16 (coalesced)
  const int r = t >> 2, q = t & 3;
  float4 v[4];
  {
    const size_t row0 = (size_t)(blockIdx.x * 32 + r) * 64;
#pragma unroll
    for (int g = 0; g < 4; ++g)
      v[g] = *(const float4*)(x + row0 + q * 4 + g * 16);
  }

  for (int it = 0; it < NSTRIPS / GRIDN; ++it) {
    __syncthreads();  // prev strip's reads of sX* done (2-wave rendezvous)

    // ---- staging: regs -> LDS (raw hi/lo split, transposed hi, x2) ----
    {
      float sq = 0.f;
#pragma unroll
      for (int g = 0; g < 4; ++g) {
        const int col = q * 4 + g * 16;
        float f0 = v[g].x, f1 = v[g].y, f2 = v[g].z, f3 = v[g].w;
        sq = fmaf(f0, f0, sq); sq = fmaf(f1, f1, sq);
        sq = fmaf(f2, f2, sq); sq = fmaf(f3, f3, sq);
        unsigned int h01 = pkbf(f0, f1), h23 = pkbf(f2, f3);
        float l0 = f0 - __uint_as_float(h01 << 16);
        float l1 = f1 - __uint_as_float(h01 & 0xffff0000u);
        float l2 = f2 - __uint_as_float(h23 << 16);
        float l3 = f3 - __uint_as_float(h23 & 0xffff0000u);
        uint2 hh = {h01, h23};
        uint2 ll = {pkbf(l0, l1), pkbf(l2, l3)};
        *(uint2*)&sXhi[r][col] = hh;
        *(uint2*)&sXlo[r][col] = ll;
        sXT[col + 0][r] = (unsigned short)(h01 & 0xffffu);
        sXT[col + 1][r] = (unsigned short)(h01 >> 16);
        sXT[col + 2][r] = (unsigned short)(h23 & 0xffffu);
        sXT[col + 3][r] = (unsigned short)(h23 >> 16);
      }
      sq += __shfl_xor(sq, 1);   // threads 4r..4r+3 share row r
      sq += __shfl_xor(sq, 2);
      if (q == 0) sX2[r] = -0.5f * LOG2E * sq;
    }
    __syncthreads();  // strip ready

    // prefetch next strip (retires under compute; drained already-complete
    // at the next top-of-loop barrier)
    if (it < NSTRIPS / GRIDN - 1) {
      const size_t nrow = (size_t)((blockIdx.x + (it + 1) * GRIDN) * 32 + r) * 64;
#pragma unroll
      for (int g = 0; g < 4; ++g)
        v[g] = *(const float4*)(x + nrow + q * 4 + g * 16);
    }

    // ---- stage A: per 16-row sub-tile, scores -> exp2 -> sPw ----
#pragma unroll
    for (int t2 = 0; t2 < 2; ++t2) {
      ushortx8 xh0 = *(const ushortx8*)&sXhi[t2 * 16 + l15][quad * 8];
      ushortx8 xh1 = *(const ushortx8*)&sXhi[t2 * 16 + l15][32 + quad * 8];
      ushortx8 xl0 = *(const ushortx8*)&sXlo[t2 * 16 + l15][quad * 8];
      ushortx8 xl1 = *(const ushortx8*)&sXlo[t2 * 16 + l15][32 + quad * 8];
      float4 m2x = *(const float4*)&sX2[t2 * 16 + quad * 4];

#pragma unroll
      for (int oo = 0; oo < 4; ++oo) {
        // two parallel MFMA chains, then combine
        floatx4 accA = {m2x.x + m2c[oo], m2x.y + m2c[oo],
                        m2x.z + m2c[oo], m2x.w + m2c[oo]};
        floatx4 accB = {0.f, 0.f, 0.f, 0.f};
        accA = mfma_bf16(xh0, __builtin_bit_cast(ushortx8, chi[oo][0]), accA);
        accB = mfma_bf16(xh1, __builtin_bit_cast(ushortx8, clo[oo][1]), accB);
        accA = mfma_bf16(xh1, __builtin_bit_cast(ushortx8, chi[oo][1]), accA);
        accB = mfma_bf16(xl0, __builtin_bit_cast(ushortx8, chi[oo][0]), accB);
        accA = mfma_bf16(xh0, __builtin_bit_cast(ushortx8, clo[oo][0]), accA);
        accB = mfma_bf16(xl1, __builtin_bit_cast(ushortx8, chi[oo][1]), accB);
        floatx4 acc = accA + accB;   // == -log2e*d/2 -> rbf = exp2(acc)
        unsigned int r01 = pkbf(EXP2F(acc[0]), EXP2F(acc[1]));
        unsigned int r23 = pkbf(EXP2F(acc[2]), EXP2F(acc[3]));
        // C/D: o' = oo*16+l15, n' = t2*16+quad*4+e (same-wave, no barrier)
        unsigned short* bp = &sPw[w][oo * 16 + l15][t2 * 16 + quad * 4];
        *(unsigned int*)(bp)     = r01;
        *(unsigned int*)(bp + 2) = r23;
      }
    }

    // ---- stage B: hist += P * x,  K = 32 (this strip) ----
    {
      ushortx8 a0 = *(const ushortx8*)&sPw[w][0 * 16 + l15][quad * 8];
      ushortx8 a1 = *(const ushortx8*)&sPw[w][1 * 16 + l15][quad * 8];
      ushortx8 a2 = *(const ushortx8*)&sPw[w][2 * 16 + l15][quad * 8];
      ushortx8 a3 = *(const ushortx8*)&sPw[w][3 * 16 + l15][quad * 8];
#pragma unroll
      for (int itl = 0; itl < 4; ++itl) {
        ushortx8 b = *(const ushortx8*)&sXT[itl * 16 + l15][quad * 8];
        hacc[0][itl] = mfma_bf16(a0, b, hacc[0][itl]);
        hacc[1][itl] = mfma_bf16(a1, b, hacc[1][itl]);
        hacc[2][itl] = mfma_bf16(a2, b, hacc[2][itl]);
        hacc[3][itl] = mfma_bf16(a3, b, hacc[3][itl]);
      }
    }
  }

  // ---- epilogue ----
  // D: i = itl*16 + l15, o = (4w+oo)*16 + quad*4 + e
  if (use_ws) {
    float* part = ws + (size_t)blockIdx.x * 8192;
#pragma unroll
    for (int oo = 0; oo < 4; ++oo)
#pragma unroll
      for (int itl = 0; itl < 4; ++itl)
#pragma unroll
        for (int e = 0; e < 4; ++e) {
          int o = (4 * w + oo) * 16 + quad * 4 + e;
          int i = itl * 16 + l15;
          part[o * 64 + i] = hacc[oo][itl][e];
        }
  } else {
#pragma unroll
    for (int oo = 0; oo < 4; ++oo)
#pragma unroll
      for (int itl = 0; itl < 4; ++itl)
#pragma unroll
        for (int e = 0; e < 4; ++e) {
          int o = (4 * w + oo) * 16 + quad * 4 + e;
          int i = itl * 16 + l15;
          atomicAdd(out + o * 64 + i, hacc[oo][itl][e]);
        }
  }
}

// sum 1024 per-block partials -> out. 32768 threads, 4 atomics per element.
__global__ void reduce_kernel(const float* __restrict__ ws, float* __restrict__ out) {
  const int tid = blockIdx.x * 256 + threadIdx.x;  // 0..32767
  const int e = tid & 8191;
  const int part = tid >> 13;                      // 0..3
  const float* p = ws + (size_t)part * 256 * 8192 + e;
  float s = 0.f;
#pragma unroll 8
  for (int b = 0; b < 256; ++b) s += p[(size_t)b * 8192];
  atomicAdd(out + e, s);
}

__global__ void zero_out_kernel(float* out, int n) {
  int i = blockIdx.x * 256 + threadIdx.x;
  if (i < n) out[i] = 0.f;
}

extern "C" void kernel_launch(void* const* d_in, const int* in_sizes, int n_in,
                              void* d_out, int out_size, void* d_ws, size_t ws_size,
                              hipStream_t stream) {
  (void)in_sizes; (void)n_in;
  const float* x = (const float*)d_in[0];        // [524288, 64]
  const float* c = (const float*)d_in[1];        // [128, 64]
  float* out = (float*)d_out;                    // [128, 64]
  float* ws  = (float*)d_ws;

  const int use_ws = (ws_size >= (size_t)GRIDN * 8192 * sizeof(float)) ? 1 : 0;

  zero_out_kernel<<<(out_size + 255) / 256, 256, 0, stream>>>(out, out_size);
  rbf_hist_kernel<<<GRIDN, 128, 0, stream>>>(x, c, out, ws, use_ws);
  if (use_ws)
    reduce_kernel<<<128, 256, 0, stream>>>(ws, out);
}

// Round 8
// 207.336 us; speedup vs baseline: 1.0339x; 1.0339x over previous
//
#include <hip/hip_runtime.h>
#include <stdint.h>

// ---------------------------------------------------------------------------
// Fused RBF histogram:  hist[o,i] = sum_n exp(-||x_n - c_o||^2 / 2) * x[n,i]
// N=524288, IN=64, OUT=128.  fp32 in/out.
//
// R8 = R7 with compile fixes:
//  - cvt_pkrtz returns __fp16-vector: bit_cast via local fp16x2 type.
//  - K=16 MFMA builtin is __builtin_amdgcn_mfma_f32_16x16x16f16 (legacy name).
//  - RNE (v_cvt_f16_f32) for x staging / c_hi / P packs (halves RTZ error).
// R7 design: LDS-pipe was the R1-R6 bottleneck (~70-90us of LDS cycles).
//  - P (rbf) stays in REGISTERS: 16x16 C/D layout (row=quad*4+e) == K=16
//    A/B-frag layout (k=quad*4+j), so stage-A output feeds stage-B directly.
//  - x^T B-frags via transpose-MFMA (D = Xchunk * I): row-major b64 reads.
//  - fp16, c-lo correction only (4 stage-A MFMAs). fp16 P underflow solved
//    by +38 bias in the exp2 arg (P*2^38); epilogue scales by 2^-38 (exact).
//  - LDS 4.7 KB (sXh + sX2). Pipes: HBM ~21us floor, MFMA ~13.5us, LDS ~8.5us.
// ---------------------------------------------------------------------------

typedef _Float16 half8v __attribute__((ext_vector_type(8)));
typedef _Float16 half4v __attribute__((ext_vector_type(4)));
typedef __fp16  fp16x2 __attribute__((ext_vector_type(2)));
typedef float floatx4 __attribute__((ext_vector_type(4)));

#define GRIDN 1024       // 4 blocks/CU x 256 CUs
#define NITER 16         // 16384 strips of 32 rows / 1024 blocks
#define LOG2E 1.4426950408889634f
#define PBIAS 38.0f                       // P scaled by 2^38 into fp16 range
#define PUNSCALE 3.637978807091713e-12f   // 2^-38 (exact power of two)

#if __has_builtin(__builtin_amdgcn_exp2f)
#define EXP2F(x) __builtin_amdgcn_exp2f(x)
#else
#define EXP2F(x) exp2f(x)
#endif

// pack two fp32 -> fp16x2, RTZ (v_cvt_pkrtz_f16_f32) — used only where the
// value is exactly representable or lo-corrected.
static __device__ __forceinline__ unsigned int pk16z(float a, float b) {
  fp16x2 h = __builtin_amdgcn_cvt_pkrtz(a, b);
  return __builtin_bit_cast(unsigned int, h);
}
// pack two fp32 -> fp16x2, RNE (v_cvt_f16_f32 x2)
static __device__ __forceinline__ unsigned int pk16(float a, float b) {
  unsigned short ha = __builtin_bit_cast(unsigned short, (_Float16)a);
  unsigned short hb = __builtin_bit_cast(unsigned short, (_Float16)b);
  return (unsigned int)ha | ((unsigned int)hb << 16);
}
static __device__ __forceinline__ half4v mkh4(unsigned int lo, unsigned int hi) {
  uint2 u{lo, hi};
  return __builtin_bit_cast(half4v, u);
}
static __device__ __forceinline__ half8v mkh8(unsigned int a, unsigned int b,
                                              unsigned int c, unsigned int d) {
  uint4 u{a, b, c, d};
  return __builtin_bit_cast(half8v, u);
}

static __device__ __forceinline__ floatx4 mfma32(half8v a, half8v b, floatx4 c) {
  return __builtin_amdgcn_mfma_f32_16x16x32_f16(a, b, c, 0, 0, 0);
}
static __device__ __forceinline__ floatx4 mfma16(half4v a, half4v b, floatx4 c) {
  return __builtin_amdgcn_mfma_f32_16x16x16f16(a, b, c, 0, 0, 0);
}

// sXh row stride 72 shorts = 144 B: multiple of 16 (aligned b128/b64 frags),
// bank step 36%32=4 words -> <=2-way conflicts on all access patterns (free).
#define LSTR 72

__global__ __launch_bounds__(128, 2) void rbf_hist_kernel(
    const float* __restrict__ x, const float* __restrict__ c,
    float* __restrict__ out, float* __restrict__ ws, int use_ws) {
  __shared__ unsigned short sXh[32][LSTR];  // fp16(x) strip, row-major [n][i]
  __shared__ float          sX2[32];        // -0.5*log2e*||x_n||^2 (fp32 exact)

  const int t    = threadIdx.x;    // 0..127
  const int lane = t & 63;
  const int w    = t >> 6;         // wave 0/1; owns o-tiles {4w..4w+3}
  const int l15  = lane & 15;
  const int quad = lane >> 4;

  // ---- one-time: c*log2e fp16 hi/lo fragments for this wave's 4 o-tiles ----
  // stage-A B-frag: B[k=i][col=o]: lane reads c[ot*16+l15][s*32+quad*8 ..+7]
  half8v chi[4][2], clo[4][2];
  float m2c[4];                    // -0.5*log2e*||c_o||^2 + PBIAS
#pragma unroll
  for (int oo = 0; oo < 4; ++oo) {
    const int ot = 4 * w + oo;
    float sq = 0.f;
#pragma unroll
    for (int s = 0; s < 2; ++s) {
      const float* p = c + (ot * 16 + l15) * 64 + s * 32 + quad * 8;
      float4 va = *(const float4*)(p);
      float4 vb = *(const float4*)(p + 4);
      float f[8] = {va.x, va.y, va.z, va.w, vb.x, vb.y, vb.z, vb.w};
      unsigned int h[4], l[4];
#pragma unroll
      for (int jp = 0; jp < 4; ++jp) {
        float a = f[2 * jp], b = f[2 * jp + 1];
        sq = fmaf(a, a, sq);
        sq = fmaf(b, b, sq);
        a *= LOG2E; b *= LOG2E;            // fold log2e into c
        unsigned int hp = pk16(a, b);      // RNE
        float ha = (float)__builtin_bit_cast(_Float16, (unsigned short)(hp & 0xffffu));
        float hb = (float)__builtin_bit_cast(_Float16, (unsigned short)(hp >> 16));
        h[jp] = hp;
        l[jp] = pk16z(a - ha, b - hb);     // c_lo correction term
      }
      chi[oo][s] = mkh8(h[0], h[1], h[2], h[3]);
      clo[oo][s] = mkh8(l[0], l[1], l[2], l[3]);
    }
    sq += __shfl_xor(sq, 16);
    sq += __shfl_xor(sq, 32);
    m2c[oo] = fmaf(-0.5f * LOG2E, sq, PBIAS);
  }

  // identity B-frag for the transpose MFMA: I[k=quad*4+j][col=l15]
  half4v iden;
  {
    float e0 = (quad * 4 + 0 == l15) ? 1.f : 0.f;
    float e1 = (quad * 4 + 1 == l15) ? 1.f : 0.f;
    float e2 = (quad * 4 + 2 == l15) ? 1.f : 0.f;
    float e3 = (quad * 4 + 3 == l15) ? 1.f : 0.f;
    iden = mkh4(pk16z(e0, e1), pk16z(e2, e3));  // exact
  }

  // persistent histogram accumulators: 4 o-tiles x 4 i-tiles (scaled by 2^38)
  floatx4 hacc[4][4];
#pragma unroll
  for (int a = 0; a < 4; ++a)
#pragma unroll
    for (int b = 0; b < 4; ++b) {
      floatx4 z = {0.f, 0.f, 0.f, 0.f};
      hacc[a][b] = z;
    }

  // staging map: thread t -> row r=t>>2 (0..31), 16 contiguous cols q*16..+15
  const int r = t >> 2, q = t & 3;
  float4 v[4];
  {
    const size_t row0 = (size_t)(blockIdx.x * 32 + r) * 64 + q * 16;
#pragma unroll
    for (int u = 0; u < 4; ++u)
      v[u] = *(const float4*)(x + row0 + u * 4);
  }

  for (int it = 0; it < NITER; ++it) {
    __syncthreads();  // prev strip's sXh reads done -> safe to overwrite

    // ---- staging: fp16 RNE convert -> LDS row-major + exact fp32 x2 ----
    {
      float sq = 0.f;
      unsigned int hw[8];
#pragma unroll
      for (int u = 0; u < 4; ++u) {
        float f0 = v[u].x, f1 = v[u].y, f2 = v[u].z, f3 = v[u].w;
        sq = fmaf(f0, f0, sq); sq = fmaf(f1, f1, sq);
        sq = fmaf(f2, f2, sq); sq = fmaf(f3, f3, sq);
        hw[2 * u]     = pk16(f0, f1);
        hw[2 * u + 1] = pk16(f2, f3);
      }
      *(uint4*)&sXh[r][q * 16]     = uint4{hw[0], hw[1], hw[2], hw[3]};
      *(uint4*)&sXh[r][q * 16 + 8] = uint4{hw[4], hw[5], hw[6], hw[7]};
      sq += __shfl_xor(sq, 1);   // threads 4r..4r+3 share row r
      sq += __shfl_xor(sq, 2);
      if (q == 0) sX2[r] = -0.5f * LOG2E * sq;
    }
    __syncthreads();  // strip ready

    // prefetch next strip (retires under compute; drained already-complete)
    if (it < NITER - 1) {
      const size_t nrow =
          (size_t)((blockIdx.x + (it + 1) * GRIDN) * 32 + r) * 64 + q * 16;
#pragma unroll
      for (int u = 0; u < 4; ++u)
        v[u] = *(const float4*)(x + nrow + u * 4);
    }

    // ---- stage A: scores -> exp2 -> P fp16 A-frags (REGISTERS, no LDS) ----
    half4v P[4][2];
#pragma unroll
    for (int t2 = 0; t2 < 2; ++t2) {
      half8v xh0 = *(const half8v*)&sXh[t2 * 16 + l15][quad * 8];
      half8v xh1 = *(const half8v*)&sXh[t2 * 16 + l15][32 + quad * 8];
      float4 m2x = *(const float4*)&sX2[t2 * 16 + quad * 4];
#pragma unroll
      for (int oo = 0; oo < 4; ++oo) {
        floatx4 accA = {m2x.x + m2c[oo], m2x.y + m2c[oo],
                        m2x.z + m2c[oo], m2x.w + m2c[oo]};
        floatx4 accB = {0.f, 0.f, 0.f, 0.f};
        accA = mfma32(xh0, chi[oo][0], accA);
        accB = mfma32(xh1, clo[oo][1], accB);
        accA = mfma32(xh1, chi[oo][1], accA);
        accB = mfma32(xh0, clo[oo][0], accB);
        floatx4 acc = accA + accB;  // == log2e*(-d/2) + 38
        // C-frag (o=l15, n=quad*4+e) == 16x16x16 A-frag (m=o, k=quad*4+j)
        P[oo][t2] = mkh4(pk16(EXP2F(acc[0]), EXP2F(acc[1])),
                         pk16(EXP2F(acc[2]), EXP2F(acc[3])));   // RNE
      }
    }

    // ---- transpose x via MFMA identity: D = X_chunk * I ----
    // A-frag: x[t2*16+l15][itl*16+quad*4 ..+3] (row-major b64 read);
    // C-frag out (i=l15, n=quad*4+e) == stage-B B-frag (col=i, k=n).
    half4v XT[4][2];
#pragma unroll
    for (int t2 = 0; t2 < 2; ++t2)
#pragma unroll
      for (int itl = 0; itl < 4; ++itl) {
        half4v ax = *(const half4v*)&sXh[t2 * 16 + l15][itl * 16 + quad * 4];
        floatx4 z = {0.f, 0.f, 0.f, 0.f};
        floatx4 d = mfma16(ax, iden, z);
        XT[itl][t2] = mkh4(pk16z(d[0], d[1]), pk16z(d[2], d[3]));  // exact
      }

    // ---- stage B: hist += P * X^T, K=16 MFMAs, zero LDS ----
#pragma unroll
    for (int t2 = 0; t2 < 2; ++t2)
#pragma unroll
      for (int oo = 0; oo < 4; ++oo)
#pragma unroll
        for (int itl = 0; itl < 4; ++itl)
          hacc[oo][itl] = mfma16(P[oo][t2], XT[itl][t2], hacc[oo][itl]);
  }

  // ---- epilogue (unscale by 2^-38, exact) ----
  // D: i = itl*16 + l15, o = (4w+oo)*16 + quad*4 + e
  if (use_ws) {
    float* part = ws + (size_t)blockIdx.x * 8192;
#pragma unroll
    for (int oo = 0; oo < 4; ++oo)
#pragma unroll
      for (int itl = 0; itl < 4; ++itl)
#pragma unroll
        for (int e = 0; e < 4; ++e) {
          int o = (4 * w + oo) * 16 + quad * 4 + e;
          int i = itl * 16 + l15;
          part[o * 64 + i] = hacc[oo][itl][e] * PUNSCALE;
        }
  } else {
#pragma unroll
    for (int oo = 0; oo < 4; ++oo)
#pragma unroll
      for (int itl = 0; itl < 4; ++itl)
#pragma unroll
        for (int e = 0; e < 4; ++e) {
          int o = (4 * w + oo) * 16 + quad * 4 + e;
          int i = itl * 16 + l15;
          atomicAdd(out + o * 64 + i, hacc[oo][itl][e] * PUNSCALE);
        }
  }
}

// sum 1024 per-block partials -> out. 32768 threads, 4 atomics per element.
__global__ void reduce_kernel(const float* __restrict__ ws, float* __restrict__ out) {
  const int tid = blockIdx.x * 256 + threadIdx.x;  // 0..32767
  const int e = tid & 8191;
  const int part = tid >> 13;                      // 0..3
  const float* p = ws + (size_t)part * 256 * 8192 + e;
  float s = 0.f;
#pragma unroll 8
  for (int b = 0; b < 256; ++b) s += p[(size_t)b * 8192];
  atomicAdd(out + e, s);
}

__global__ void zero_out_kernel(float* out, int n) {
  int i = blockIdx.x * 256 + threadIdx.x;
  if (i < n) out[i] = 0.f;
}

extern "C" void kernel_launch(void* const* d_in, const int* in_sizes, int n_in,
                              void* d_out, int out_size, void* d_ws, size_t ws_size,
                              hipStream_t stream) {
  (void)in_sizes; (void)n_in;
  const float* x = (const float*)d_in[0];        // [524288, 64]
  const float* c = (const float*)d_in[1];        // [128, 64]
  float* out = (float*)d_out;                    // [128, 64]
  float* ws  = (float*)d_ws;

  const int use_ws = (ws_size >= (size_t)GRIDN * 8192 * sizeof(float)) ? 1 : 0;

  zero_out_kernel<<<(out_size + 255) / 256, 256, 0, stream>>>(out, out_size);
  rbf_hist_kernel<<<GRIDN, 128, 0, stream>>>(x, c, out, ws, use_ws);
  if (use_ws)
    reduce_kernel<<<128, 256, 0, stream>>>(ws, out);
}